// Round 11
// baseline (255.423 us; speedup 1.0000x reference)
//
#include <hip/hip_runtime.h>
#include <hip/hip_bf16.h>
#include <math.h>

// out[b] = max_o( 2 * gelu_tanh( x[b,:] . weight[o,:] + bias[o] ) )
// 4096 x 4096 x 4096, fp32 in, fp32 out[4096].
//
// Round 11: B-operand direct-from-global. Pipe audit: R8's LDS pipe carried
// reads 2300 + gload_lds writes 1000 cyc/tile vs MFMA 2483 -- saturated.
// B frags (row=l15, 8 contig k) load straight from the K-contiguous weight
// array (SGPR base + per-lane voffset), double-buffered in regs one K-tile
// ahead, drained by the tile-end vmcnt(0). A stays global_load_lds + T2
// swizzle. LDS = 64 KiB (A only), 1 barrier/tile, per-tile LDS pipe 1792
// cyc < MFMA 2483 -> MFMA becomes the floor.

typedef unsigned short u16;
typedef short bf16x8 __attribute__((ext_vector_type(8)));   // 8 bf16 = 4 VGPRs
typedef float f32x4 __attribute__((ext_vector_type(4)));
typedef unsigned short ushort8 __attribute__((ext_vector_type(8)));

#define MDIM 4096
#define NDIM 4096
#define KD   4096
#define BM 256
#define BN 256
#define BK 64
#define NKT (KD / BK)          // 64 K-tiles
#define NTN (NDIM / BN)        // 16 column tiles
#define HT  (128 * 64)         // u16 per A half-tile (16 KB)

__device__ __forceinline__ u16 f2bf(float f) {
  unsigned int u = __float_as_uint(f);
  u += 0x7fffu + ((u >> 16) & 1u);
  return (u16)(u >> 16);
}

__global__ void f32_to_bf16_kernel(const float* __restrict__ in0,
                                   const float* __restrict__ in1,
                                   u16* __restrict__ out0,
                                   u16* __restrict__ out1, int n8) {
  int i = blockIdx.x * blockDim.x + threadIdx.x;
  int stride = gridDim.x * blockDim.x;
  for (; i < 2 * n8; i += stride) {
    const float* in = (i < n8) ? in0 : in1;
    u16* out = (i < n8) ? out0 : out1;
    int k = (i < n8) ? i : i - n8;
    const float4* p = (const float4*)in + (size_t)k * 2;
    float4 a = p[0];
    float4 b = p[1];
    ushort8 o;
    o[0] = f2bf(a.x); o[1] = f2bf(a.y); o[2] = f2bf(a.z); o[3] = f2bf(a.w);
    o[4] = f2bf(b.x); o[5] = f2bf(b.y); o[6] = f2bf(b.z); o[7] = f2bf(b.w);
    ((ushort8*)out)[k] = o;
  }
}

__device__ __forceinline__ void gload_lds16(const u16* g, u16* l) {
  __builtin_amdgcn_global_load_lds(
      (__attribute__((address_space(1))) void*)(g),
      (__attribute__((address_space(3))) void*)(l), 16, 0, 0);
}

#define LDSOFF(buf, half) ((((buf)*2) + (half)) * HT)
#define SBAR0 __builtin_amdgcn_sched_barrier(0)

// Stage A-tile (256x64) of next K-step into buffer c: 4 gloads/thread.
#define STAGE_A(c)                                                        \
  {                                                                       \
    _Pragma("unroll")                                                     \
    for (int q = 0; q < 4; ++q) {                                         \
      gload_lds16(gp[q], sm + LDSOFF((c), q >> 1) + (q & 1) * 4096 + wdof); \
      gp[q] += BK;                                                        \
    }                                                                     \
  }

// Load 8 B fragments (4n x 2ks) for the NEXT tile from global into regs;
// SGPR base per n (readfirstlane) + per-lane voffset, advanced per tile.
#define LOAD_B(dst)                                                       \
  {                                                                       \
    _Pragma("unroll")                                                     \
    for (int ks = 0; ks < 2; ++ks)                                        \
      _Pragma("unroll")                                                   \
      for (int n = 0; n < 4; ++n)                                         \
        dst[ks * 4 + n] = *(const bf16x8*)(Bb[n] + vko[ks]);              \
    vko[0] += BK;                                                         \
    vko[1] += BK;                                                         \
  }

#define READ_A8(dst, c, mh)                                               \
  {                                                                       \
    _Pragma("unroll")                                                     \
    for (int ks = 0; ks < 2; ++ks)                                        \
      _Pragma("unroll")                                                   \
      for (int mm = 0; mm < 4; ++mm)                                      \
        dst[ks * 4 + mm] =                                                \
            *(const bf16x8*)(ARB[(c)][ks] + ((mh)*4 + mm) * 1024);        \
  }

// 32 MFMA: half mh x 4n x 2ks (ks outer: 16 independent chains)
#define MFMAH(afv, bfv, mh)                                               \
  {                                                                       \
    __builtin_amdgcn_s_setprio(1);                                        \
    _Pragma("unroll")                                                     \
    for (int ks = 0; ks < 2; ++ks)                                        \
      _Pragma("unroll")                                                   \
      for (int mm = 0; mm < 4; ++mm)                                      \
        _Pragma("unroll")                                                 \
        for (int n = 0; n < 4; ++n)                                       \
          acc[(mh)*4 + mm][n] = __builtin_amdgcn_mfma_f32_16x16x32_bf16(  \
              afv[ks * 4 + mm], bfv[ks * 4 + n], acc[(mh)*4 + mm][n],     \
              0, 0, 0);                                                   \
    __builtin_amdgcn_s_setprio(0);                                        \
  }

// One K-tile on buffer c. bfC: this tile's B frags; bfN: next tile's.
#define TILE(c, bfC, bfN, ST, LAST)                                       \
  {                                                                       \
    READ_A8(af, c, 0)                                                     \
    if (ST) { LOAD_B(bfN) STAGE_A((c) ^ 1) }                              \
    SBAR0;                                                                \
    asm volatile("s_waitcnt lgkmcnt(0)" ::: "memory");                    \
    SBAR0;                                                                \
    MFMAH(af, bfC, 0)                                                     \
    SBAR0;                                                                \
    READ_A8(af, c, 1)                                                     \
    SBAR0;                                                                \
    asm volatile("s_waitcnt lgkmcnt(0)" ::: "memory");                    \
    SBAR0;                                                                \
    MFMAH(af, bfC, 1)                                                     \
    SBAR0;                                                                \
    if (!LAST) { asm volatile("s_waitcnt vmcnt(0)" ::: "memory"); }       \
    __builtin_amdgcn_s_barrier();                                         \
  }

__global__ __launch_bounds__(512, 2) void gemm_gelu_max_kernel(
    const u16* __restrict__ A,    // x bf16 [4096][4096], K contiguous
    const u16* __restrict__ Bw,   // weight bf16 [4096][4096], K contiguous
    const float* __restrict__ bias,
    float* __restrict__ partials) {
  __shared__ __align__(16) u16 sm[2 * 2 * HT];  // 64 KiB (A only)
  __shared__ float pmx[8][128];                  // 4 KiB

  const int t = threadIdx.x;
  const int wave = t >> 6;
  const int lane = t & 63;
  const int warp_m = wave >> 2;        // A half
  const int warp_n = wave & 3;         // 64-col group
  const int l15 = lane & 15;
  const int l4 = lane >> 4;
  const int l7 = lane & 7;
  const int wdof = wave * 512;         // wave's gload_lds dest slot (u16)

  // T1: XCD-aware 2D swizzle (bid%8 -> XCD; XCD owns 4x8 tile region)
  const int bid = blockIdx.x;
  const int c8 = bid & 7;
  const int j = bid >> 3;
  const int tx = ((c8 & 3) << 2) + (j & 3);    // 0..15
  const int ty = ((c8 >> 2) << 3) + (j >> 2);  // 0..15
  const int brow = ty * BM;
  const int bcol = tx * BN;

  // A per-thread swizzled 16B-chunk offsets (u16 elems) for k-slice 0/1
  const int cko0 = ((l4 ^ l7) << 3);
  const int cko1 = (((4 + l4) ^ l7) << 3);

  // A LDS read bases per (buffer, ks)
  const u16* ARB[2][2];
#pragma unroll
  for (int c = 0; c < 2; ++c) {
    ARB[c][0] = sm + LDSOFF(c, warp_m) + l15 * 64 + cko0;
    ARB[c][1] = sm + LDSOFF(c, warp_m) + l15 * 64 + cko1;
  }

  // A running global staging pointers (pre-swizzled source, rule #21)
  const u16* gp[4];
#pragma unroll
  for (int it = 0; it < 2; ++it) {
    const int chunk = it * 512 + t;
    const int r = chunk >> 3;
    const int sw = ((chunk & 7) ^ (r & 7)) << 3;
    gp[0 + it] = A + (size_t)(brow + r) * KD + sw;        // rows 0..127
    gp[2 + it] = A + (size_t)(brow + 128 + r) * KD + sw;  // rows 128..255
  }

  // B: SGPR bases per n (wave-uniform via readfirstlane) + per-lane voffset
  const u16* Bb[4];
#pragma unroll
  for (int n = 0; n < 4; ++n) {
    int bofs = __builtin_amdgcn_readfirstlane((bcol + warp_n * 64 + n * 16) * KD);
    Bb[n] = Bw + (size_t)(unsigned)bofs;
  }
  int vko[2];
  vko[0] = l15 * KD + l4 * 8;        // ks0
  vko[1] = l15 * KD + 32 + l4 * 8;   // ks1

  f32x4 acc[8][4] = {};   // per-wave 128x64 output
  bf16x8 af[8], bfE[8], bfO[8];

  // prologue: A tile0 -> buf0; B tile0 -> bfE
  STAGE_A(0)
  LOAD_B(bfE)
  asm volatile("s_waitcnt vmcnt(0)" ::: "memory");
  __builtin_amdgcn_s_barrier();

  for (int kt2 = 0; kt2 < NKT / 2 - 1; ++kt2) {   // kt = 0..61
    TILE(0, bfE, bfO, 1, 0)
    TILE(1, bfO, bfE, 1, 0)
  }
  TILE(0, bfE, bfO, 1, 0)    // kt 62: stages A63->buf1, loads B63->bfO
  TILE(1, bfO, bfE, 0, 1)    // kt 63

  // ---- epilogue: bias + 2*gelu_tanh, row-max over cols
  // C/D layout per 16x16 frag: col = l15, row = l4*4 + j
  float rmax_[8][4];
#pragma unroll
  for (int m = 0; m < 8; ++m)
#pragma unroll
    for (int j2 = 0; j2 < 4; ++j2) rmax_[m][j2] = -1e30f;

#pragma unroll
  for (int n = 0; n < 4; ++n) {
    const float bv = bias[bcol + warp_n * 64 + n * 16 + l15];
#pragma unroll
    for (int m = 0; m < 8; ++m) {
#pragma unroll
      for (int j2 = 0; j2 < 4; ++j2) {
        float x = acc[m][n][j2] + bv;
        float u = 0.7978845608f * x * (1.0f + 0.044715f * x * x);
        float e = exp2f(u * 2.8853900817779268f);   // 2*log2(e)
        float r = __builtin_amdgcn_rcpf(e + 1.0f);
        float g = 2.0f * x * (1.0f - r);
        rmax_[m][j2] = fmaxf(rmax_[m][j2], g);
      }
    }
  }

#pragma unroll
  for (int m = 0; m < 8; ++m) {
#pragma unroll
    for (int j2 = 0; j2 < 4; ++j2) {
      float v = rmax_[m][j2];
      v = fmaxf(v, __shfl_xor(v, 1, 64));
      v = fmaxf(v, __shfl_xor(v, 2, 64));
      v = fmaxf(v, __shfl_xor(v, 4, 64));
      v = fmaxf(v, __shfl_xor(v, 8, 64));
      if (l15 == 0) pmx[wave][m * 16 + l4 * 4 + j2] = v;
    }
  }
  __syncthreads();

  if (t < 256) {
    int gm = t >> 7;
    int r = t & 127;
    float v = fmaxf(fmaxf(pmx[gm * 4 + 0][r], pmx[gm * 4 + 1][r]),
                    fmaxf(pmx[gm * 4 + 2][r], pmx[gm * 4 + 3][r]));
    partials[(size_t)tx * MDIM + brow + t] = v;
  }
}

__global__ void rowmax_kernel(const float* __restrict__ partials,
                              float* __restrict__ out) {
  int r = blockIdx.x * blockDim.x + threadIdx.x;
  if (r < MDIM) {
    float m = -1e30f;
#pragma unroll
    for (int tt = 0; tt < NTN; ++tt) m = fmaxf(m, partials[(size_t)tt * MDIM + r]);
    out[r] = m;
  }
}

extern "C" void kernel_launch(void* const* d_in, const int* in_sizes, int n_in,
                              void* d_out, int out_size, void* d_ws, size_t ws_size,
                              hipStream_t stream) {
  const float* x = (const float*)d_in[0];
  const float* w = (const float*)d_in[1];
  const float* bias = (const float*)d_in[2];
  float* out = (float*)d_out;

  u16* xb = (u16*)d_ws;
  u16* wb = xb + (size_t)MDIM * KD;
  float* partials = (float*)(wb + (size_t)NDIM * KD);

  const int n8 = (MDIM * KD) / 8;
  f32_to_bf16_kernel<<<2048, 256, 0, stream>>>(x, w, xb, wb, n8);

  gemm_gelu_max_kernel<<<dim3(256), 512, 0, stream>>>(xb, wb, bias, partials);

  rowmax_kernel<<<MDIM / 256, 256, 0, stream>>>(partials, out);
}

// Round 12
// 171.881 us; speedup vs baseline: 1.4860x; 1.4860x over previous
//
#include <hip/hip_runtime.h>
#include <hip/hip_bf16.h>
#include <math.h>

// out[b] = max_o( 2 * gelu_tanh( x[b,:] . weight[o,:] + bias[o] ) )
// 4096 x 4096 x 4096, fp32 in, fp32 out[4096].
//
// Round 12: m201-derived 4-phase/K-tile schedule with even 8/4/8/4 reads.
// Quadrants ordered (mh, ks): q(0,k0),q(1,k0),q(0,k1),q(1,k1) -- B frags
// read once per ks (4), A per (mh,ks) (4) -> every phase has 16 MFMA AND a
// read window, preserving the wave-stagger overlap (waves exit lgkmcnt(0)
// staggered; MFMA overlaps later waves' LDS service). LDS split in k-half
// quarters (Ak0/Ak1/Bk0/Bk1, 256x32, 64B rows): fragment reads naturally
// conflict-free (16-bank row stride), NO swizzle either side (rule 21).
// Stage 1 half-tile per phase; counted vmcnt(4) at ph2/ph4 only.

typedef unsigned short u16;
typedef short bf16x8 __attribute__((ext_vector_type(8)));   // 8 bf16 = 4 VGPRs
typedef float f32x4 __attribute__((ext_vector_type(4)));
typedef unsigned short ushort8 __attribute__((ext_vector_type(8)));

#define MDIM 4096
#define NDIM 4096
#define KD   4096
#define BM 256
#define BN 256
#define BK 64
#define NKT (KD / BK)          // 64 K-tiles
#define NTN (NDIM / BN)        // 16 column tiles
#define QT  8192               // u16 per quarter (256 rows x 32 k = 16 KB)
#define BUFSZ (4 * QT)         // 64 KB per buffer (u16 count 32768)

__device__ __forceinline__ u16 f2bf(float f) {
  unsigned int u = __float_as_uint(f);
  u += 0x7fffu + ((u >> 16) & 1u);
  return (u16)(u >> 16);
}

__global__ void f32_to_bf16_kernel(const float* __restrict__ in0,
                                   const float* __restrict__ in1,
                                   u16* __restrict__ out0,
                                   u16* __restrict__ out1, int n8) {
  int i = blockIdx.x * blockDim.x + threadIdx.x;
  int stride = gridDim.x * blockDim.x;
  for (; i < 2 * n8; i += stride) {
    const float* in = (i < n8) ? in0 : in1;
    u16* out = (i < n8) ? out0 : out1;
    int k = (i < n8) ? i : i - n8;
    const float4* p = (const float4*)in + (size_t)k * 2;
    float4 a = p[0];
    float4 b = p[1];
    ushort8 o;
    o[0] = f2bf(a.x); o[1] = f2bf(a.y); o[2] = f2bf(a.z); o[3] = f2bf(a.w);
    o[4] = f2bf(b.x); o[5] = f2bf(b.y); o[6] = f2bf(b.z); o[7] = f2bf(b.w);
    ((ushort8*)out)[k] = o;
  }
}

__device__ __forceinline__ void gload_lds16(const u16* g, u16* l) {
  __builtin_amdgcn_global_load_lds(
      (__attribute__((address_space(1))) void*)(g),
      (__attribute__((address_space(3))) void*)(l), 16, 0, 0);
}

#define SBAR0 __builtin_amdgcn_sched_barrier(0)

// quarter byte-order in LDS: h0=Ak0 @0, h1=Bk0 @2*QT, h2=Ak1 @QT, h3=Bk1 @3*QT
#define QOFF(h) ((h) == 0 ? 0 : ((h) == 1 ? 2 * QT : ((h) == 2 ? QT : 3 * QT)))

// Stage one 256x32 half (h) of the next K-tile into buffer `buf`:
// 2 gload_lds/thread, linear dest, advance running pointers by BK.
#define STAGE_HALF(buf, h)                                                \
  {                                                                       \
    gload_lds16(gp[(h)*2 + 0], sm + (buf)*BUFSZ + QOFF(h) + wdof);        \
    gp[(h)*2 + 0] += BK;                                                  \
    gload_lds16(gp[(h)*2 + 1], sm + (buf)*BUFSZ + QOFF(h) + 4096 + wdof); \
    gp[(h)*2 + 1] += BK;                                                  \
  }

#define READ_A4(dst, c, ks, mh)                                           \
  {                                                                       \
    _Pragma("unroll")                                                     \
    for (int mm = 0; mm < 4; ++mm)                                        \
      dst[mm] = *(const bf16x8*)(ARB[(c)][(ks)] + ((mh)*4 + mm) * 512);   \
  }

#define READ_B4(dst, c, ks)                                               \
  {                                                                       \
    _Pragma("unroll")                                                     \
    for (int n = 0; n < 4; ++n)                                           \
      dst[n] = *(const bf16x8*)(BRB[(c)][(ks)] + n * 512);                \
  }

// 16 MFMA: quadrant (mh) x 4n at one ks
#define MFMAQ(afv, bfv, mh)                                               \
  {                                                                       \
    __builtin_amdgcn_s_setprio(1);                                        \
    _Pragma("unroll")                                                     \
    for (int mm = 0; mm < 4; ++mm)                                        \
      _Pragma("unroll")                                                   \
      for (int n = 0; n < 4; ++n)                                         \
        acc[(mh)*4 + mm][n] = __builtin_amdgcn_mfma_f32_16x16x32_bf16(    \
            afv[mm], bfv[n], acc[(mh)*4 + mm][n], 0, 0, 0);               \
    __builtin_amdgcn_s_setprio(0);                                        \
  }

#define LGKM0                                                             \
  SBAR0;                                                                  \
  asm volatile("s_waitcnt lgkmcnt(0)" ::: "memory");                      \
  SBAR0;

#define VM4 asm volatile("s_waitcnt vmcnt(4)" ::: "memory");
#define VM0 asm volatile("s_waitcnt vmcnt(0)" ::: "memory");
#define VMNONE

// One K-tile on buffer c. ST: stage tile t+1 halves into buf c^1.
// ph1: rdA(mh0,k0)+rdB(k0); stage h0'; lgkm0; q(0,k0); bar
// ph2: rdA(mh1,k0);         stage h1'; lgkm0; q(1,k0); W2; bar
// ph3: rdA(mh0,k1)+rdB(k1); stage h2'; lgkm0; q(0,k1); bar
// ph4: rdA(mh1,k1);         stage h3'; lgkm0; q(1,k1); W4; bar
#define TILE(c, ST, W2, W4)                                               \
  {                                                                       \
    READ_A4(afP, c, 0, 0)                                                 \
    READ_B4(bfP, c, 0)                                                    \
    if (ST) { STAGE_HALF((c) ^ 1, 0) }                                    \
    LGKM0                                                                 \
    MFMAQ(afP, bfP, 0)                                                    \
    SBAR0;                                                                \
    __builtin_amdgcn_s_barrier();                                         \
    READ_A4(afQ, c, 0, 1)                                                 \
    if (ST) { STAGE_HALF((c) ^ 1, 1) }                                    \
    LGKM0                                                                 \
    MFMAQ(afQ, bfP, 1)                                                    \
    SBAR0;                                                                \
    W2                                                                    \
    __builtin_amdgcn_s_barrier();                                         \
    READ_A4(afP, c, 1, 0)                                                 \
    READ_B4(bfQ, c, 1)                                                    \
    if (ST) { STAGE_HALF((c) ^ 1, 2) }                                    \
    LGKM0                                                                 \
    MFMAQ(afP, bfQ, 0)                                                    \
    SBAR0;                                                                \
    __builtin_amdgcn_s_barrier();                                         \
    READ_A4(afQ, c, 1, 1)                                                 \
    if (ST) { STAGE_HALF((c) ^ 1, 3) }                                    \
    LGKM0                                                                 \
    MFMAQ(afQ, bfQ, 1)                                                    \
    SBAR0;                                                                \
    W4                                                                    \
    __builtin_amdgcn_s_barrier();                                         \
  }

__global__ __launch_bounds__(512, 2) void gemm_gelu_max_kernel(
    const u16* __restrict__ A,    // x bf16 [4096][4096], K contiguous
    const u16* __restrict__ Bw,   // weight bf16 [4096][4096], K contiguous
    const float* __restrict__ bias,
    float* __restrict__ partials) {
  __shared__ __align__(16) u16 sm[2 * BUFSZ];  // 128 KiB
  __shared__ float pmx[8][128];                 // 4 KiB

  const int t = threadIdx.x;
  const int wave = t >> 6;
  const int lane = t & 63;
  const int warp_m = wave >> 2;        // A 128-row half
  const int warp_n = wave & 3;         // 64-col group
  const int l15 = lane & 15;
  const int l4 = lane >> 4;
  const int wdof = wave * 512;         // wave's gload_lds dest slot (u16)

  // T1: XCD-aware 2D swizzle (bid%8 -> XCD; XCD owns 4x8 tile region)
  const int bid = blockIdx.x;
  const int c8 = bid & 7;
  const int j = bid >> 3;
  const int tx = ((c8 & 3) << 2) + (j & 3);    // 0..15
  const int ty = ((c8 >> 2) << 3) + (j >> 2);  // 0..15
  const int brow = ty * BM;
  const int bcol = tx * BN;

  // LDS read bases per (buffer, ks): 64B rows, naturally conflict-free
  const u16* ARB[2][2];
  const u16* BRB[2][2];
#pragma unroll
  for (int c = 0; c < 2; ++c) {
#pragma unroll
    for (int ks = 0; ks < 2; ++ks) {
      ARB[c][ks] = sm + c * BUFSZ + QOFF(2 * ks) +
                   (warp_m * 128 + l15) * 32 + l4 * 8;
      BRB[c][ks] = sm + c * BUFSZ + QOFF(2 * ks + 1) +
                   (warp_n * 64 + l15) * 32 + l4 * 8;
    }
  }

  // running global staging pointers: gp[h*2+it], h: 0=Ak0,1=Bk0,2=Ak1,3=Bk1
  const u16* gp[8];
#pragma unroll
  for (int it = 0; it < 2; ++it) {
    const int chunk = it * 512 + t;
    const int r = chunk >> 2;          // 0..255
    const int kc = (chunk & 3) * 8;    // 16B chunk within 32-k row
    gp[0 + it] = A  + (size_t)(brow + r) * KD + kc;        // Ak0
    gp[2 + it] = Bw + (size_t)(bcol + r) * KD + kc;        // Bk0
    gp[4 + it] = A  + (size_t)(brow + r) * KD + 32 + kc;   // Ak1
    gp[6 + it] = Bw + (size_t)(bcol + r) * KD + 32 + kc;   // Bk1
  }

  f32x4 acc[8][4] = {};   // per-wave 128x64 output
  bf16x8 afP[4], afQ[4], bfP[4], bfQ[4];

  // prologue: all 4 halves of tile 0 -> buf0 (order h0,h1,h2,h3);
  // vmcnt(4) = h0,h1 landed, h2,h3 in flight (steady-state entry).
  STAGE_HALF(0, 0)
  STAGE_HALF(0, 1)
  STAGE_HALF(0, 2)
  STAGE_HALF(0, 3)
  asm volatile("s_waitcnt vmcnt(4)" ::: "memory");
  __builtin_amdgcn_s_barrier();

  for (int kt2 = 0; kt2 < NKT / 2 - 1; ++kt2) {   // tiles 0..61
    TILE(0, 1, VM4, VM4)
    TILE(1, 1, VM4, VM4)
  }
  TILE(0, 1, VM4, VM4)     // tile 62 (stages tile 63 into buf1)
  TILE(1, 0, VM0, VMNONE)  // tile 63 (ph2 drains tile-62 stages)

  // ---- epilogue: bias + 2*gelu_tanh, row-max over cols
  // C/D layout per 16x16 frag: col = l15, row = l4*4 + j
  float rmax_[8][4];
#pragma unroll
  for (int m = 0; m < 8; ++m)
#pragma unroll
    for (int j2 = 0; j2 < 4; ++j2) rmax_[m][j2] = -1e30f;

#pragma unroll
  for (int n = 0; n < 4; ++n) {
    const float bv = bias[bcol + warp_n * 64 + n * 16 + l15];
#pragma unroll
    for (int m = 0; m < 8; ++m) {
#pragma unroll
      for (int j2 = 0; j2 < 4; ++j2) {
        float x = acc[m][n][j2] + bv;
        float u = 0.7978845608f * x * (1.0f + 0.044715f * x * x);
        float e = exp2f(u * 2.8853900817779268f);   // 2*log2(e)
        float r = __builtin_amdgcn_rcpf(e + 1.0f);
        float g = 2.0f * x * (1.0f - r);
        rmax_[m][j2] = fmaxf(rmax_[m][j2], g);
      }
    }
  }

#pragma unroll
  for (int m = 0; m < 8; ++m) {
#pragma unroll
    for (int j2 = 0; j2 < 4; ++j2) {
      float v = rmax_[m][j2];
      v = fmaxf(v, __shfl_xor(v, 1, 64));
      v = fmaxf(v, __shfl_xor(v, 2, 64));
      v = fmaxf(v, __shfl_xor(v, 4, 64));
      v = fmaxf(v, __shfl_xor(v, 8, 64));
      if (l15 == 0) pmx[wave][m * 16 + l4 * 4 + j2] = v;
    }
  }
  __syncthreads();

  if (t < 256) {
    int gm = t >> 7;
    int r = t & 127;
    float v = fmaxf(fmaxf(pmx[gm * 4 + 0][r], pmx[gm * 4 + 1][r]),
                    fmaxf(pmx[gm * 4 + 2][r], pmx[gm * 4 + 3][r]));
    partials[(size_t)tx * MDIM + brow + t] = v;
  }
}

__global__ void rowmax_kernel(const float* __restrict__ partials,
                              float* __restrict__ out) {
  int r = blockIdx.x * blockDim.x + threadIdx.x;
  if (r < MDIM) {
    float m = -1e30f;
#pragma unroll
    for (int tt = 0; tt < NTN; ++tt) m = fmaxf(m, partials[(size_t)tt * MDIM + r]);
    out[r] = m;
  }
}

extern "C" void kernel_launch(void* const* d_in, const int* in_sizes, int n_in,
                              void* d_out, int out_size, void* d_ws, size_t ws_size,
                              hipStream_t stream) {
  const float* x = (const float*)d_in[0];
  const float* w = (const float*)d_in[1];
  const float* bias = (const float*)d_in[2];
  float* out = (float*)d_out;

  u16* xb = (u16*)d_ws;
  u16* wb = xb + (size_t)MDIM * KD;
  float* partials = (float*)(wb + (size_t)NDIM * KD);

  const int n8 = (MDIM * KD) / 8;
  f32_to_bf16_kernel<<<2048, 256, 0, stream>>>(x, w, xb, wb, n8);

  gemm_gelu_max_kernel<<<dim3(256), 512, 0, stream>>>(xb, wb, bias, partials);

  rowmax_kernel<<<MDIM / 256, 256, 0, stream>>>(partials, out);
}